// Round 13
// baseline (89.232 us; speedup 1.0000x reference)
//
#include <hip/hip_runtime.h>
#include <hip/hip_bf16.h>
#include <hip/hip_fp16.h>
#include <math.h>

#define BB 8
#define TT 2048
#define DD 512
#define SD 256
#define OD 64
#define CHUNK 32
#define NC 64          // TT/CHUNK
#define CB 64          // binding-scan chunk
#define NCB 32         // TT/CB
#define MM (BB*TT)     // 16384
#define KCAT 320       // states(256) | obind(64)

typedef __attribute__((ext_vector_type(8))) short bf16x8_t;
typedef __attribute__((ext_vector_type(4))) float f32x4;

// async global->LDS, 16B per lane. LDS dest must be wave-uniform base (+lane*16 by HW).
__device__ __forceinline__ void gload_lds16(const void* gsrc, void* ldst) {
    __builtin_amdgcn_global_load_lds(
        (const __attribute__((address_space(1))) unsigned int*)gsrc,
        (__attribute__((address_space(3))) unsigned int*)ldst,
        16, 0, 0);
}

// load 4 consecutive __half as float4 (two 4B loads)
__device__ __forceinline__ float4 ldh4(const __half* p) {
    __half2 a = *(const __half2*)p;
    __half2 b = *(const __half2*)(p + 2);
    float2 fa = __half22float2(a), fb = __half22float2(b);
    return make_float4(fa.x, fa.y, fb.x, fb.y);
}

// ---------------------------------------------------------------------------
// conv_w: Wcat[768][512] = [gate|in|v|k|q|pad]^T bf16 + bias_cat[768].
// ---------------------------------------------------------------------------
__global__ __launch_bounds__(256) void conv_w(
    const float* __restrict__ gate_W, const float* __restrict__ gate_b,
    const float* __restrict__ in_W,   const float* __restrict__ in_b,
    const float* __restrict__ opv_W,  const float* __restrict__ opk_W,
    const float* __restrict__ opq_W,
    const float* __restrict__ opv_b,  const float* __restrict__ opk_b,
    const float* __restrict__ opq_b,
    __hip_bfloat16* __restrict__ Wcat, float* __restrict__ bias_cat)
{
    int idx = blockIdx.x * 256 + threadIdx.x;
    if (idx < 393216) {                       // Wcat [768][512]
        int n = idx >> 9, k = idx & 511;
        float v;
        if (n < 256)       v = gate_W[k * 256 + n];
        else if (n < 512)  v = in_W[k * 256 + (n - 256)];
        else if (n < 704) {
            int h = (n - 512) >> 6, j = (n - 512) & 63;
            const float* W = (h == 0) ? opv_W : (h == 1) ? opk_W : opq_W;
            v = W[k * 64 + j];
        } else v = 0.f;
        Wcat[idx] = __float2bfloat16(v);
        return;
    }
    idx -= 393216;
    if (idx < 768) {
        float v;
        if (idx < 256)      v = gate_b[idx];
        else if (idx < 512) v = in_b[idx - 256];
        else if (idx < 704) {
            int h = (idx - 512) >> 6, j = (idx - 512) & 63;
            v = (h == 0) ? opv_b[j] : (h == 1) ? opk_b[j] : opq_b[j];
        } else v = 0.f;
        bias_cat[idx] = v;
    }
}

// ---------------------------------------------------------------------------
// Projection GEMM, DEPTH-3 pipeline: [gi|vkq](fp16) = x(fp32) @ Wcat^T + b.
// 128x128 tile, BK=32, 512 threads / 8 waves (2x4), wave tile 64x32.
// 3 A-register sets (p,q,r; issue tile T+3 at step T), 2 A LDS buffers,
// 4 B LDS buffers (gload_lds), steady-state vmcnt(6). 48KB LDS = 3 blocks/CU.
// ---------------------------------------------------------------------------
__global__ __launch_bounds__(512, 6) void gemm_proj(
    const float* __restrict__ A,             // x [M][K] fp32
    const __hip_bfloat16* __restrict__ Bt,   // Wcat [N][K]
    const float* __restrict__ bias,
    __half* __restrict__ out0,
    __half* __restrict__ out1,               // cols >= n0, stride N-n0
    int M, int N, int K, int n0, int sigCols)
{
    constexpr int BM = 128, BK = 32;
    __shared__ alignas(16) __hip_bfloat16 Abuf[2][BM * BK];   // 2x8KB
    __shared__ alignas(16) __hip_bfloat16 Bbuf[4][BM * BK];   // 4x8KB
    const int tid = threadIdx.x;
    const int lane = tid & 63, wid = tid >> 6;
    const int wr = wid >> 2, wc = wid & 3;           // 2x4 wave grid, 64x32 tiles
    const int nbn = N >> 7;
    const int chunk = gridDim.x >> 3;
    const int b = blockIdx.x;
    const int orig = (b & 7) * chunk + (b >> 3);     // XCD-contiguous chunks
    const int bm = (orig / nbn) * BM, bn = (orig % nbn) * BM;
    const int l15 = lane & 15, hgr = lane >> 4;

    // staging: granule g = tid (512 granules = 128 rows x 4 slots)
    const int grow = tid >> 2, gslot = tid & 3;
    const int gsw = gslot ^ ((grow >> 1) & 3);
    const float* srcA = A + (size_t)(bm + grow) * K + gslot * 8;
    const int wOffA = grow * 64 + gsw * 16;                  // swizzled LDS bytes
    const __hip_bfloat16* srcB = Bt + (size_t)(bn + grow) * K + gsw * 8;  // pre-swz src
    const int ldsOffB = (tid & ~63) * 16;                    // linear, wave-uniform

    int offA[4], offB[2];
    #pragma unroll
    for (int mi = 0; mi < 4; ++mi) {
        int r = wr * 64 + mi * 16 + l15;
        offA[mi] = r * 64 + (hgr ^ ((r >> 1) & 3)) * 16;
    }
    #pragma unroll
    for (int nj = 0; nj < 2; ++nj) {
        int r = wc * 32 + nj * 16 + l15;
        offB[nj] = r * 64 + (hgr ^ ((r >> 1) & 3)) * 16;
    }

    f32x4 acc[4][2] = {};
    const int nk = K / BK;    // 16
    float4 pA0, pA1, qA0, qA1, rA0, rA1;   // three reg sets (tile % 3)

#define WRITE_A(IDX, R0, R1) do { \
        alignas(16) __hip_bfloat16 h_[8] = { \
            __float2bfloat16((R0).x), __float2bfloat16((R0).y), \
            __float2bfloat16((R0).z), __float2bfloat16((R0).w), \
            __float2bfloat16((R1).x), __float2bfloat16((R1).y), \
            __float2bfloat16((R1).z), __float2bfloat16((R1).w)}; \
        *(float4*)((char*)&Abuf[(IDX)][0] + wOffA) = *(float4*)h_; \
    } while (0)

#define FRAG_MFMA(T) do { \
        const char* ab_ = (const char*)&Abuf[(T) & 1][0]; \
        const char* bb_ = (const char*)&Bbuf[(T) & 3][0]; \
        bf16x8_t af_[4], bf_[2]; \
        _Pragma("unroll") \
        for (int mi = 0; mi < 4; ++mi) af_[mi] = *(const bf16x8_t*)(ab_ + offA[mi]); \
        _Pragma("unroll") \
        for (int nj = 0; nj < 2; ++nj) bf_[nj] = *(const bf16x8_t*)(bb_ + offB[nj]); \
        _Pragma("unroll") \
        for (int mi = 0; mi < 4; ++mi) \
            _Pragma("unroll") \
            for (int nj = 0; nj < 2; ++nj) \
                acc[mi][nj] = __builtin_amdgcn_mfma_f32_16x16x32_bf16( \
                    af_[mi], bf_[nj], acc[mi][nj], 0, 0, 0); \
    } while (0)

    // issue loads for tile T+3 into reg set (I0,I1) + Bbuf[(T+3)&3]
#define ISSUE3(T, I0, I1) do { \
        int k3_ = ((T) + 3) * BK; \
        I0 = *(const float4*)(srcA + k3_); \
        I1 = *(const float4*)(srcA + k3_ + 4); \
        gload_lds16(srcB + k3_, (char*)&Bbuf[((T) + 3) & 3][0] + ldsOffB); \
    } while (0)

    // compute step T; write A(T+1) LDS from reg set (W0,W1); counted wait; barrier
#define STEP_TAIL(T, W0, W1, VMLINE) do { \
        FRAG_MFMA(T); \
        WRITE_A(((T) + 1) & 1, W0, W1); \
        asm volatile(VMLINE ::: "memory"); \
        __builtin_amdgcn_sched_barrier(0); \
        __builtin_amdgcn_s_barrier(); \
        __builtin_amdgcn_sched_barrier(0); \
    } while (0)

    // prologue: issue tiles 0,1,2 into p,q,r + Bbuf[0..2]
    pA0 = *(const float4*)(srcA);
    pA1 = *(const float4*)(srcA + 4);
    gload_lds16(srcB, (char*)&Bbuf[0][0] + ldsOffB);
    qA0 = *(const float4*)(srcA + BK);
    qA1 = *(const float4*)(srcA + BK + 4);
    gload_lds16(srcB + BK, (char*)&Bbuf[1][0] + ldsOffB);
    rA0 = *(const float4*)(srcA + 2 * BK);
    rA1 = *(const float4*)(srcA + 2 * BK + 4);
    gload_lds16(srcB + 2 * BK, (char*)&Bbuf[2][0] + ldsOffB);
    WRITE_A(0, pA0, pA1);                       // implicit wait on tile-0 A loads
    asm volatile("s_waitcnt vmcnt(6) lgkmcnt(0)" ::: "memory");   // B0 done
    __builtin_amdgcn_sched_barrier(0);
    __builtin_amdgcn_s_barrier();
    __builtin_amdgcn_sched_barrier(0);

    // main loop: steps 0..11 (all ISSUE3 targets <= tile 14 < nk... tile T+3 <= 14)
    for (int tt = 0; tt < 12; tt += 3) {
        // T ≡ 0 (mod 3): issue tile T+3 -> p ; write A(T+1) from q
        ISSUE3(tt, pA0, pA1);
        STEP_TAIL(tt, qA0, qA1, "s_waitcnt vmcnt(6) lgkmcnt(0)");
        // T ≡ 1: issue -> q ; write A(T+1) from r
        ISSUE3(tt + 1, qA0, qA1);
        STEP_TAIL(tt + 1, rA0, rA1, "s_waitcnt vmcnt(6) lgkmcnt(0)");
        // T ≡ 2: issue -> r ; write A(T+1) from p
        ISSUE3(tt + 2, rA0, rA1);
        STEP_TAIL(tt + 2, pA0, pA1, "s_waitcnt vmcnt(6) lgkmcnt(0)");
    }
    // peel T=12: last issue (tile 15 -> p)
    ISSUE3(12, pA0, pA1);
    STEP_TAIL(12, qA0, qA1, "s_waitcnt vmcnt(6) lgkmcnt(0)");
    // peel T=13: no issue; outstanding = A15x2 + B15 = 3 -> vmcnt(3) forces B14
    STEP_TAIL(13, rA0, rA1, "s_waitcnt vmcnt(3) lgkmcnt(0)");
    // peel T=14: write A15 from p (implicit wait); vmcnt(0) forces B15
    STEP_TAIL(14, pA0, pA1, "s_waitcnt vmcnt(0) lgkmcnt(0)");
    // peel T=15: compute only
    FRAG_MFMA(15);

#undef STEP_TAIL
#undef ISSUE3
#undef FRAG_MFMA
#undef WRITE_A

    const int n1 = N - n0;
    #pragma unroll
    for (int mi = 0; mi < 4; ++mi) {
        #pragma unroll
        for (int nj = 0; nj < 2; ++nj) {
            int col = bn + wc * 32 + nj * 16 + l15;
            int r0 = bm + wr * 64 + mi * 16 + hgr * 4;
            float bv = bias[col];
            #pragma unroll
            for (int e = 0; e < 4; ++e) {
                int row = r0 + e;
                float val = acc[mi][nj][e] + bv;
                if (col < n0) {
                    if (col < sigCols) val = 1.f / (1.f + expf(-val));
                    out0[(size_t)row * n0 + col] = __float2half(val);
                } else {
                    out1[(size_t)row * n1 + (col - n0)] = __float2half(val);
                }
            }
        }
    }
}

// ---------------------------------------------------------------------------
// Scan / bind device bodies. gi: [M][512] fp16 (g | in). vkq: [M][256] fp16.
// ---------------------------------------------------------------------------
__device__ void scan_pass1_body(int blk,
    const __half* __restrict__ gi,
    float* __restrict__ ca_last, float* __restrict__ wb_last)
{
    int idx = blk * 256 + threadIdx.x;        // 131072
    int sd = idx & 255;
    int c  = (idx >> 8) & 63;
    int b  = idx >> 14;
    size_t base = ((size_t)(b * TT + c * CHUNK)) * 512;
    float prod = 1.f, wb = 0.f;
    for (int i = 0; i < CHUNK; ++i) {
        size_t off = base + (size_t)i * 512;
        float g  = __half2float(gi[off + sd]);
        float il = __half2float(gi[off + 256 + sd]);
        float a = fmaxf(g, 1e-6f);
        prod *= a;
        wb += (1.f - g) * il / fmaxf(prod, 1e-8f);
    }
    int cidx = (b * NC + c) * SD + sd;
    ca_last[cidx] = prod;
    wb_last[cidx] = wb;
}

// writes states bf16 into cat[row][0..255], stride KCAT
__device__ void scan_pass3_body(int blk,
    const __half* __restrict__ gi, const float* __restrict__ h_prev,
    __hip_bfloat16* __restrict__ cat)
{
    int idx = blk * 256 + threadIdx.x;        // 131072
    int sd = idx & 255;
    int c  = (idx >> 8) & 63;
    int b  = idx >> 14;
    size_t base = ((size_t)(b * TT + c * CHUNK)) * 512;
    size_t obase = ((size_t)(b * TT + c * CHUNK)) * KCAT + sd;
    float h = h_prev[(b * NC + c) * SD + sd];
    float prod = 1.f, wb = 0.f;
    for (int i = 0; i < CHUNK; ++i) {
        size_t off = base + (size_t)i * 512;
        float g  = __half2float(gi[off + sd]);
        float il = __half2float(gi[off + 256 + sd]);
        float a = fmaxf(g, 1e-6f);
        prod *= a;
        wb += (1.f - g) * il / fmaxf(prod, 1e-8f);
        cat[obase + (size_t)i * KCAT] = __float2bfloat16(prod * (h + wb));
    }
}

#define LST 68
__device__ void bind_p1_body(int bc,
    const __half* __restrict__ vkq, const float* __restrict__ op_decay,
    float* __restrict__ o, float* __restrict__ dS,
    float* B1, float* B2, float* B3, float* l2d)
{
    const int b = bc >> 5, c = bc & 31;
    const size_t base = ((size_t)b * TT + (size_t)c * CB) * 256;
    const size_t obase = ((size_t)b * TT + (size_t)c * CB) * OD;
    const int tid = threadIdx.x;
    if (tid < 64) l2d[tid] = log2f(1.f / (1.f + expf(-op_decay[tid])));
    const int lr = tid >> 4, lc = (tid & 15) << 2;
    #pragma unroll
    for (int rr = 0; rr < 4; ++rr) {
        int t = lr + rr * 16;
        float4 qv = ldh4(&vkq[base + t * 256 + 128 + lc]);
        float4 kv = ldh4(&vkq[base + t * 256 + 64 + lc]);
        float q4[4] = {qv.x, qv.y, qv.z, qv.w};
        float k4[4] = {kv.x, kv.y, kv.z, kv.w};
        #pragma unroll
        for (int j = 0; j < 4; ++j) {
            B1[(lc + j) * LST + t] = q4[j];
            B2[(lc + j) * LST + t] = k4[j];
        }
    }
    __syncthreads();
    const int tx = tid & 15, ty = tid >> 4;
    {
        float a_acc[4][4] = {};
        for (int d = 0; d < 64; ++d) {
            float4 q4 = *(const float4*)&B1[d * LST + 4 * ty];
            float4 k4 = *(const float4*)&B2[d * LST + 4 * tx];
            float qr[4] = {q4.x, q4.y, q4.z, q4.w};
            float kr[4] = {k4.x, k4.y, k4.z, k4.w};
            #pragma unroll
            for (int r = 0; r < 4; ++r)
                #pragma unroll
                for (int s = 0; s < 4; ++s)
                    a_acc[r][s] = fmaf(qr[r], kr[s], a_acc[r][s]);
        }
        __syncthreads();
        #pragma unroll
        for (int s = 0; s < 4; ++s) {
            int ss = 4 * tx + s;
            float w[4];
            #pragma unroll
            for (int r = 0; r < 4; ++r)
                w[r] = (ss <= 4 * ty + r) ? a_acc[r][s] : 0.f;
            *(float4*)&B3[ss * LST + 4 * ty] = *(float4*)w;
        }
    }
    #pragma unroll
    for (int rr = 0; rr < 4; ++rr) {
        int m = lr + rr * 16;
        float4 vv = ldh4(&vkq[base + m * 256 + 0 + lc]);
        float4 kv = ldh4(&vkq[base + m * 256 + 64 + lc]);
        float v4[4] = {vv.x, vv.y, vv.z, vv.w};
        #pragma unroll
        for (int j = 0; j < 4; ++j)
            v4[j] *= exp2f(-(float)m * l2d[lc + j]);
        *(float4*)&B1[m * LST + lc] = *(float4*)v4;
        float k4[4] = {kv.x, kv.y, kv.z, kv.w};
        *(float4*)&B2[m * LST + lc] = *(float4*)k4;
    }
    __syncthreads();
    {
        float p[4][4] = {};
        for (int s = 0; s < 64; ++s) {
            float4 a4 = *(const float4*)&B3[s * LST + 4 * ty];
            float4 v4 = *(const float4*)&B1[s * LST + 4 * tx];
            float ar[4] = {a4.x, a4.y, a4.z, a4.w};
            float vr[4] = {v4.x, v4.y, v4.z, v4.w};
            #pragma unroll
            for (int r = 0; r < 4; ++r)
                #pragma unroll
                for (int i2 = 0; i2 < 4; ++i2)
                    p[r][i2] = fmaf(ar[r], vr[i2], p[r][i2]);
        }
        #pragma unroll
        for (int r = 0; r < 4; ++r) {
            int t = 4 * ty + r;
            float w[4];
            #pragma unroll
            for (int i2 = 0; i2 < 4; ++i2)
                w[i2] = exp2f((float)t * l2d[4 * tx + i2]) * p[r][i2];
            *(float4*)&o[obase + t * OD + 4 * tx] = *(float4*)w;
        }
    }
    {
        float sacc[4][4] = {};
        for (int m = 0; m < 64; ++m) {
            float4 v4 = *(const float4*)&B1[m * LST + 4 * ty];
            float4 k4 = *(const float4*)&B2[m * LST + 4 * tx];
            float vr[4] = {v4.x, v4.y, v4.z, v4.w};
            float kr[4] = {k4.x, k4.y, k4.z, k4.w};
            #pragma unroll
            for (int r = 0; r < 4; ++r)
                #pragma unroll
                for (int j = 0; j < 4; ++j)
                    sacc[r][j] = fmaf(vr[r], kr[j], sacc[r][j]);
        }
        float* dSb = dS + (size_t)bc * 4096;
        #pragma unroll
        for (int r = 0; r < 4; ++r) {
            int i = 4 * ty + r;
            float scale = exp2f(63.f * l2d[i]);
            float w[4];
            #pragma unroll
            for (int j2 = 0; j2 < 4; ++j2)
                w[j2] = scale * sacc[r][j2];
            *(float4*)&dSb[i * 64 + 4 * tx] = *(float4*)w;
        }
    }
}

// o_final(bf16 into cat[row][256+i]) = o_intra + dec^(l+1) * (Q @ Sstart^T)
__device__ void bind_p3_body(int bc,
    const __half* __restrict__ vkq, const float* __restrict__ Sstart,
    const float* __restrict__ op_decay, const float* __restrict__ o,
    __hip_bfloat16* __restrict__ cat,
    float* B1, float* B2, float* l2d)
{
    const int b = bc >> 5, c = bc & 31;
    const size_t base = ((size_t)b * TT + (size_t)c * CB) * 256;
    const size_t obase = ((size_t)b * TT + (size_t)c * CB) * OD;
    const size_t cbase = ((size_t)b * TT + (size_t)c * CB) * KCAT + 256;
    const int tid = threadIdx.x;
    if (tid < 64) l2d[tid] = log2f(1.f / (1.f + expf(-op_decay[tid])));
    const int lr = tid >> 4, lc = (tid & 15) << 2;
    const float* Sb = Sstart + (size_t)bc * 4096;
    #pragma unroll
    for (int rr = 0; rr < 4; ++rr) {
        int t = lr + rr * 16;
        float4 qv = ldh4(&vkq[base + t * 256 + 128 + lc]);
        float4 sv = *(const float4*)&Sb[t * 64 + lc];
        float q4[4] = {qv.x, qv.y, qv.z, qv.w};
        float s4[4] = {sv.x, sv.y, sv.z, sv.w};
        #pragma unroll
        for (int j = 0; j < 4; ++j) {
            B1[(lc + j) * LST + t] = q4[j];
            B2[(lc + j) * LST + t] = s4[j];
        }
    }
    __syncthreads();
    const int tx = tid & 15, ty = tid >> 4;
    float acc[4][4] = {};
    for (int j = 0; j < 64; ++j) {
        float4 q4 = *(const float4*)&B1[j * LST + 4 * ty];
        float4 s4 = *(const float4*)&B2[j * LST + 4 * tx];
        float qr[4] = {q4.x, q4.y, q4.z, q4.w};
        float sr[4] = {s4.x, s4.y, s4.z, s4.w};
        #pragma unroll
        for (int r = 0; r < 4; ++r)
            #pragma unroll
            for (int i2 = 0; i2 < 4; ++i2)
                acc[r][i2] = fmaf(qr[r], sr[i2], acc[r][i2]);
    }
    #pragma unroll
    for (int r = 0; r < 4; ++r) {
        int l = 4 * ty + r;
        alignas(8) __hip_bfloat16 w[4];
        #pragma unroll
        for (int i2 = 0; i2 < 4; ++i2) {
            int i = 4 * tx + i2;
            float val = o[obase + l * OD + i] + exp2f((float)(l + 1) * l2d[i]) * acc[r][i2];
            w[i2] = __float2bfloat16(val);
        }
        *(float2*)&cat[cbase + l * KCAT + 4 * tx] = *(float2*)w;
    }
}

// fused1: blocks 0-255 -> bind_p1, blocks 256-767 -> scan_pass1
__global__ __launch_bounds__(256) void fused1(
    const __half* __restrict__ gi, const __half* __restrict__ vkq,
    const float* __restrict__ op_decay,
    float* __restrict__ ca_last, float* __restrict__ wb_last,
    float* __restrict__ o_intra, float* __restrict__ dS)
{
    __shared__ float B1[64 * LST];
    __shared__ float B2[64 * LST];
    __shared__ float B3[64 * LST];
    __shared__ float l2d[64];
    const int bid = blockIdx.x;
    if (bid < 256) bind_p1_body(bid, vkq, op_decay, o_intra, dS, B1, B2, B3, l2d);
    else           scan_pass1_body(bid - 256, gi, ca_last, wb_last);
}

// fused2: blocks 0-127 -> bind_p2 carry; 128-135 -> scan_pass2;
//         blocks 136+  -> Wcomb/bias_comb prep (idle capacity)
__global__ __launch_bounds__(256) void fused2(
    const float* __restrict__ dS, const float* __restrict__ op_decay,
    float* __restrict__ Sstart,
    const float* __restrict__ ca_last, const float* __restrict__ wb_last,
    float* __restrict__ h_prev,
    const float* __restrict__ out_W, const float* __restrict__ out_b,
    const float* __restrict__ opout_W, const float* __restrict__ opout_b,
    __hip_bfloat16* __restrict__ Wcomb, float* __restrict__ bias_comb)
{
    const int bid = blockIdx.x;
    if (bid < 128) {
        int idx = bid * 256 + threadIdx.x;   // 32768
        int j = idx & 63, i = (idx >> 6) & 63, b = idx >> 12;
        float dec = 1.f / (1.f + expf(-op_decay[i]));
        float d64 = exp2f(64.f * log2f(dec));
        float S = 0.f;
        for (int c = 0; c < NCB; ++c) {
            size_t o = (((size_t)b * NCB + c) * 4096) + i * 64 + j;
            Sstart[o] = S;
            S = d64 * S + dS[o];
        }
    } else if (bid < 136) {
        int idx = (bid - 128) * 256 + threadIdx.x;   // 2048
        int sd = idx & 255;
        int b  = idx >> 8;
        float h = 0.f;
        for (int c = 0; c < NC; ++c) {
            int o = (b * NC + c) * SD + sd;
            h_prev[o] = h;
            h = ca_last[o] * (h + wb_last[o]);
        }
    } else {
        int idx = (bid - 136) * 256 + threadIdx.x;
        if (idx < 163840) {                       // Wcomb [512][320]
            int n = idx / KCAT, k = idx % KCAT;
            float v = (k < 256) ? out_W[k * 512 + n] : opout_W[(k - 256) * 512 + n];
            Wcomb[idx] = __float2bfloat16(v);
            return;
        }
        idx -= 163840;
        if (idx < 512) bias_comb[idx] = out_b[idx] + opout_b[idx];
    }
}

// fused3: blocks 0-255 -> bind_p3 (cat cols 256-319), 256-767 -> scan_pass3 (cols 0-255)
__global__ __launch_bounds__(256) void fused3(
    const __half* __restrict__ gi, const float* __restrict__ h_prev,
    const __half* __restrict__ vkq, const float* __restrict__ Sstart,
    const float* __restrict__ op_decay, const float* __restrict__ o_intra,
    __hip_bfloat16* __restrict__ cat)
{
    __shared__ float B1[64 * LST];
    __shared__ float B2[64 * LST];
    __shared__ float l2d[64];
    const int bid = blockIdx.x;
    if (bid < 256) bind_p3_body(bid, vkq, Sstart, op_decay, o_intra, cat, B1, B2, l2d);
    else           scan_pass3_body(bid - 256, gi, h_prev, cat);
}

// ---------------------------------------------------------------------------
// Fused output GEMM + residual + LayerNorm.
// y = LN(x + cat @ Wcomb^T + bias_comb) * ln_g + ln_b
// BM=32, BN=512 (full rows per block), BK=32, 512 threads (8 waves, 1x8),
// wave tile 32x64, double-buffered global_load_lds with granule swizzle.
// ---------------------------------------------------------------------------
__global__ __launch_bounds__(512) void outgemm_ln(
    const __hip_bfloat16* __restrict__ cat,    // [M][320]
    const __hip_bfloat16* __restrict__ Wcomb,  // [512][320]
    const float* __restrict__ bias_comb,
    const float* __restrict__ x,               // [M][512]
    const float* __restrict__ lng, const float* __restrict__ lnb,
    float* __restrict__ y)
{
    constexpr int BM = 32, BK = 32, NN = 512;
    __shared__ alignas(16) __hip_bfloat16 As[2][BM * BK];     // 2x2KB
    __shared__ alignas(16) __hip_bfloat16 Bs[2][NN * BK];     // 2x32KB
    __shared__ float psum[8][BM], psum2[8][BM], mvmu[BM], mvrs[BM];
    const int tid = threadIdx.x;
    const int lane = tid & 63, wid = tid >> 6;
    const int l15 = lane & 15, hgr = lane >> 4;
    const int bm = blockIdx.x * BM;

    // A staging (waves 0-1 only)
    const __hip_bfloat16* srcA = cat;
    int ldsOffA = 0;
    {
        int gg = (wid & 1) * 64 + lane;
        int row = gg >> 2, sl = (gg & 3) ^ ((row >> 1) & 3);
        srcA = cat + (size_t)(bm + row) * KCAT + sl * 8;
        ldsOffA = (wid & 1) * 1024;
    }
    // B staging: 4 calls per wave
    const __hip_bfloat16* srcB[4];
    int ldsOffB[4];
    #pragma unroll
    for (int c = 0; c < 4; ++c) {
        int gg = (wid * 4 + c) * 64 + lane;
        int row = gg >> 2, sl = (gg & 3) ^ ((row >> 1) & 3);
        srcB[c] = Wcomb + (size_t)row * KCAT + sl * 8;
        ldsOffB[c] = (wid * 4 + c) * 1024;
    }
    int offA[2], offB[4];
    #pragma unroll
    for (int mi = 0; mi < 2; ++mi) {
        int r = mi * 16 + l15;
        offA[mi] = r * 64 + (hgr ^ ((r >> 1) & 3)) * 16;
    }
    #pragma unroll
    for (int nj = 0; nj < 4; ++nj) {
        int n = wid * 64 + nj * 16 + l15;
        offB[nj] = n * 64 + (hgr ^ ((n >> 1) & 3)) * 16;
    }

    f32x4 acc[2][4] = {};
    constexpr int nk = KCAT / BK;   // 10

    if (wid < 2) gload_lds16(srcA, (char*)&As[0][0] + ldsOffA);
    #pragma unroll
    for (int c = 0; c < 4; ++c) gload_lds16(srcB[c], (char*)&Bs[0][0] + ldsOffB[c]);
    __syncthreads();

    int cur = 0;
    for (int t = 0; t < nk; ++t) {
        if (t + 1 < nk) {
            int k0 = (t + 1) * BK;
            if (wid < 2) gload_lds16(srcA + k0, (char*)&As[cur ^ 1][0] + ldsOffA);
            #pragma unroll
            for (int c = 0; c < 4; ++c)
                gload_lds16(srcB[c] + k0, (char*)&Bs[cur ^ 1][0] + ldsOffB[c]);
        }
        bf16x8_t af[2], bfr[4];
        #pragma unroll
        for (int mi = 0; mi < 2; ++mi)
            af[mi] = *(const bf16x8_t*)((const char*)&As[cur][0] + offA[mi]);
        #pragma unroll
        for (int nj = 0; nj < 4; ++nj)
            bfr[nj] = *(const bf16x8_t*)((const char*)&Bs[cur][0] + offB[nj]);
        #pragma unroll
        for (int mi = 0; mi < 2; ++mi)
            #pragma unroll
            for (int nj = 0; nj < 4; ++nj)
                acc[mi][nj] = __builtin_amdgcn_mfma_f32_16x16x32_bf16(
                    af[mi], bfr[nj], acc[mi][nj], 0, 0, 0);
        __syncthreads();
        cur ^= 1;
    }

    // epilogue: + bias + x residual
    #pragma unroll
    for (int nj = 0; nj < 4; ++nj) {
        int col = wid * 64 + nj * 16 + l15;
        float bc_ = bias_comb[col];
        #pragma unroll
        for (int mi = 0; mi < 2; ++mi) {
            int r0 = bm + mi * 16 + hgr * 4;
            #pragma unroll
            for (int e = 0; e < 4; ++e)
                acc[mi][nj][e] += bc_ + x[(size_t)(r0 + e) * DD + col];
        }
    }
    // per-row sums over this wave's 64 cols
    float s[8], s2[8];
    #pragma unroll
    for (int mi = 0; mi < 2; ++mi)
        #pragma unroll
        for (int e = 0; e < 4; ++e) {
            float a = 0.f, b2 = 0.f;
            #pragma unroll
            for (int nj = 0; nj < 4; ++nj) {
                float v = acc[mi][nj][e];
                a += v; b2 += v * v;
            }
            s[mi * 4 + e] = a; s2[mi * 4 + e] = b2;
        }
    #pragma unroll
    for (int off = 1; off <= 8; off <<= 1)
        #pragma unroll
        for (int i = 0; i < 8; ++i) {
            s[i]  += __shfl_xor(s[i], off);
            s2[i] += __shfl_xor(s2[i], off);
        }
    if (l15 == 0) {
        #pragma unroll
        for (int mi = 0; mi < 2; ++mi)
            #pragma unroll
            for (int e = 0; e < 4; ++e) {
                int lr = mi * 16 + hgr * 4 + e;
                psum[wid][lr]  = s[mi * 4 + e];
                psum2[wid][lr] = s2[mi * 4 + e];
            }
    }
    __syncthreads();
    if (tid < BM) {
        float tot = 0.f, tot2 = 0.f;
        #pragma unroll
        for (int w2 = 0; w2 < 8; ++w2) { tot += psum[w2][tid]; tot2 += psum2[w2][tid]; }
        float mu = tot * (1.f / 512.f);
        float var = tot2 * (1.f / 512.f) - mu * mu;
        mvmu[tid] = mu;
        mvrs[tid] = rsqrtf(var + 1e-5f);
    }
    __syncthreads();
    #pragma unroll
    for (int nj = 0; nj < 4; ++nj) {
        int col = wid * 64 + nj * 16 + l15;
        float g = lng[col], bb = lnb[col];
        #pragma unroll
        for (int mi = 0; mi < 2; ++mi) {
            #pragma unroll
            for (int e = 0; e < 4; ++e) {
                int lr = mi * 16 + hgr * 4 + e;
                y[(size_t)(bm + lr) * DD + col] =
                    (acc[mi][nj][e] - mvmu[lr]) * mvrs[lr] * g + bb;
            }
        }
    }
}

// ---------------------------------------------------------------------------
extern "C" void kernel_launch(void* const* d_in, const int* in_sizes, int n_in,
                              void* d_out, int out_size, void* d_ws, size_t ws_size,
                              hipStream_t stream)
{
    const float* x       = (const float*)d_in[0];
    const float* gate_W  = (const float*)d_in[1];
    const float* gate_b  = (const float*)d_in[2];
    const float* in_W    = (const float*)d_in[3];
    const float* in_b    = (const float*)d_in[4];
    const float* out_W   = (const float*)d_in[5];
    const float* out_b   = (const float*)d_in[6];
    const float* opv_W   = (const float*)d_in[7];
    const float* opv_b   = (const float*)d_in[8];
    const float* opk_W   = (const float*)d_in[9];
    const float* opk_b   = (const float*)d_in[10];
    const float* opq_W   = (const float*)d_in[11];
    const float* opq_b   = (const float*)d_in[12];
    const float* op_dec  = (const float*)d_in[13];
    const float* opout_W = (const float*)d_in[14];
    const float* opout_b = (const float*)d_in[15];
    const float* ln_g    = (const float*)d_in[16];
    const float* ln_b    = (const float*)d_in[17];
    float* y = (float*)d_out;

    char* w = (char*)d_ws;
    auto alloc = [&](size_t bytes) { char* p = w; w += (bytes + 255) & ~(size_t)255; return p; };
    __half* gi       = (__half*)alloc((size_t)MM * 512 * 2);
    __half* vkq      = (__half*)alloc((size_t)MM * 256 * 2);
    float* o_intra   = (float*)alloc((size_t)MM * 64 * 4);
    float* ca_last   = (float*)alloc((size_t)BB * NC * SD * 4);
    float* wb_last   = (float*)alloc((size_t)BB * NC * SD * 4);
    float* h_prev    = (float*)alloc((size_t)BB * NC * SD * 4);
    float* dS        = (float*)alloc((size_t)BB * NCB * 4096 * 4);
    float* Sstart    = (float*)alloc((size_t)BB * NCB * 4096 * 4);
    float* bias_cat  = (float*)alloc(768 * 4);
    float* bias_comb = (float*)alloc(512 * 4);
    __hip_bfloat16* cat   = (__hip_bfloat16*)alloc((size_t)MM * KCAT * 2);
    __hip_bfloat16* Wcat  = (__hip_bfloat16*)alloc((size_t)768 * 512 * 2);
    __hip_bfloat16* Wcomb = (__hip_bfloat16*)alloc((size_t)512 * KCAT * 2);

    // 1: weight prep (Wcat + bias_cat only)
    hipLaunchKernelGGL(conv_w, dim3((393216 + 768 + 255) / 256), dim3(256), 0, stream,
                       gate_W, gate_b, in_W, in_b, opv_W, opk_W, opq_W,
                       opv_b, opk_b, opq_b, Wcat, bias_cat);
    // 2: fused projection from fp32 x (fp16 outputs, XCD-swizzled grid 768 = 8*96)
    hipLaunchKernelGGL(gemm_proj, dim3(6 * (MM / 128)), dim3(512), 0, stream,
                       x, Wcat, bias_cat, gi, vkq,
                       MM, 768, 512, 512, 256);
    // 3: bind_p1 || scan_pass1
    hipLaunchKernelGGL(fused1, dim3(768), dim3(256), 0, stream,
                       gi, vkq, op_dec, ca_last, wb_last, o_intra, dS);
    // 4: carry scans + Wcomb prep in idle blocks
    hipLaunchKernelGGL(fused2, dim3(136 + (163840 + 512 + 255) / 256), dim3(256), 0, stream,
                       dS, op_dec, Sstart, ca_last, wb_last, h_prev,
                       out_W, out_b, opout_W, opout_b, Wcomb, bias_comb);
    // 5: bind_p3 || scan_pass3 -> cat[M][320] bf16
    hipLaunchKernelGGL(fused3, dim3(768), dim3(256), 0, stream,
                       gi, h_prev, vkq, Sstart, op_dec, o_intra, cat);
    // 6: y = LN(x + cat @ Wcomb^T + bias_comb)
    hipLaunchKernelGGL(outgemm_ln, dim3(MM / 32), dim3(512), 0, stream,
                       cat, Wcomb, bias_comb, x, ln_g, ln_b, y);
}

// Round 14
// 87.442 us; speedup vs baseline: 1.0205x; 1.0205x over previous
//
#include <hip/hip_runtime.h>
#include <hip/hip_bf16.h>
#include <hip/hip_fp16.h>
#include <math.h>

#define BB 8
#define TT 2048
#define DD 512
#define SD 256
#define OD 64
#define CHUNK 32
#define NC 64          // TT/CHUNK
#define CB 64          // binding-scan chunk
#define NCB 32         // TT/CB
#define MM (BB*TT)     // 16384
#define KCAT 320       // states(256) | obind(64)

typedef __attribute__((ext_vector_type(8))) short bf16x8_t;
typedef __attribute__((ext_vector_type(4))) float f32x4;

// async global->LDS, 16B per lane. LDS dest must be wave-uniform base (+lane*16 by HW).
__device__ __forceinline__ void gload_lds16(const void* gsrc, void* ldst) {
    __builtin_amdgcn_global_load_lds(
        (const __attribute__((address_space(1))) unsigned int*)gsrc,
        (__attribute__((address_space(3))) unsigned int*)ldst,
        16, 0, 0);
}

// load 4 consecutive __half as float4 (two 4B loads)
__device__ __forceinline__ float4 ldh4(const __half* p) {
    __half2 a = *(const __half2*)p;
    __half2 b = *(const __half2*)(p + 2);
    float2 fa = __half22float2(a), fb = __half22float2(b);
    return make_float4(fa.x, fa.y, fb.x, fb.y);
}

// ---------------------------------------------------------------------------
// conv_w: Wcat[768][512] = [gate|in|v|k|q|pad]^T bf16 + bias_cat[768].
// (Wcomb/bias_comb prep lives in fused2's idle blocks.)
// ---------------------------------------------------------------------------
__global__ __launch_bounds__(256) void conv_w(
    const float* __restrict__ gate_W, const float* __restrict__ gate_b,
    const float* __restrict__ in_W,   const float* __restrict__ in_b,
    const float* __restrict__ opv_W,  const float* __restrict__ opk_W,
    const float* __restrict__ opq_W,
    const float* __restrict__ opv_b,  const float* __restrict__ opk_b,
    const float* __restrict__ opq_b,
    __hip_bfloat16* __restrict__ Wcat, float* __restrict__ bias_cat)
{
    int idx = blockIdx.x * 256 + threadIdx.x;
    if (idx < 393216) {                       // Wcat [768][512]
        int n = idx >> 9, k = idx & 511;
        float v;
        if (n < 256)       v = gate_W[k * 256 + n];
        else if (n < 512)  v = in_W[k * 256 + (n - 256)];
        else if (n < 704) {
            int h = (n - 512) >> 6, j = (n - 512) & 63;
            const float* W = (h == 0) ? opv_W : (h == 1) ? opk_W : opq_W;
            v = W[k * 64 + j];
        } else v = 0.f;
        Wcat[idx] = __float2bfloat16(v);
        return;
    }
    idx -= 393216;
    if (idx < 768) {
        float v;
        if (idx < 256)      v = gate_b[idx];
        else if (idx < 512) v = in_b[idx - 256];
        else if (idx < 704) {
            int h = (idx - 512) >> 6, j = (idx - 512) & 63;
            v = (h == 0) ? opv_b[j] : (h == 1) ? opk_b[j] : opq_b[j];
        } else v = 0.f;
        bias_cat[idx] = v;
    }
}

// ---------------------------------------------------------------------------
// Projection GEMM (R8 proven, EXACT — no setprio): [gi|vkq](fp16) = x @ Wcat^T.
// 128x128 tile, BK=32, 512 threads / 8 waves (2x4), wave tile 64x32.
// DEPTH-2 PIPELINE: 3 LDS buffers, raw s_barrier + counted vmcnt(3).
// ---------------------------------------------------------------------------
__global__ __launch_bounds__(512, 6) void gemm_proj(
    const float* __restrict__ A,             // x [M][K] fp32
    const __hip_bfloat16* __restrict__ Bt,   // Wcat [N][K]
    const float* __restrict__ bias,
    __half* __restrict__ out0,
    __half* __restrict__ out1,               // cols >= n0, stride N-n0
    int M, int N, int K, int n0, int sigCols)
{
    constexpr int BM = 128, BK = 32;
    __shared__ alignas(16) __hip_bfloat16 Abuf[3][BM * BK];   // 3x8KB
    __shared__ alignas(16) __hip_bfloat16 Bbuf[3][BM * BK];
    const int tid = threadIdx.x;
    const int lane = tid & 63, wid = tid >> 6;
    const int wr = wid >> 2, wc = wid & 3;           // 2x4 wave grid, 64x32 tiles
    const int nbn = N >> 7;
    const int chunk = gridDim.x >> 3;
    const int b = blockIdx.x;
    const int orig = (b & 7) * chunk + (b >> 3);     // XCD-contiguous chunks
    const int bm = (orig / nbn) * BM, bn = (orig % nbn) * BM;
    const int l15 = lane & 15, hgr = lane >> 4;

    // staging: granule g = tid (512 granules = 128 rows x 4 slots)
    const int grow = tid >> 2, gslot = tid & 3;
    const int gsw = gslot ^ ((grow >> 1) & 3);
    const float* srcA = A + (size_t)(bm + grow) * K + gslot * 8;
    const int wOffA = grow * 64 + gsw * 16;                  // swizzled LDS bytes
    const __hip_bfloat16* srcB = Bt + (size_t)(bn + grow) * K + gsw * 8;  // pre-swz src
    const int ldsOffB = (tid & ~63) * 16;                    // linear, wave-uniform

    int offA[4], offB[2];
    #pragma unroll
    for (int mi = 0; mi < 4; ++mi) {
        int r = wr * 64 + mi * 16 + l15;
        offA[mi] = r * 64 + (hgr ^ ((r >> 1) & 3)) * 16;
    }
    #pragma unroll
    for (int nj = 0; nj < 2; ++nj) {
        int r = wc * 32 + nj * 16 + l15;
        offB[nj] = r * 64 + (hgr ^ ((r >> 1) & 3)) * 16;
    }

    f32x4 acc[4][2] = {};
    const int nk = K / BK;    // 16
    float4 pA0, pA1, qA0, qA1;   // two reg sets (even steps / odd steps)

#define WRITE_A(IDX, R0, R1) do { \
        alignas(16) __hip_bfloat16 h_[8] = { \
            __float2bfloat16((R0).x), __float2bfloat16((R0).y), \
            __float2bfloat16((R0).z), __float2bfloat16((R0).w), \
            __float2bfloat16((R1).x), __float2bfloat16((R1).y), \
            __float2bfloat16((R1).z), __float2bfloat16((R1).w)}; \
        *(float4*)((char*)&Abuf[(IDX)][0] + wOffA) = *(float4*)h_; \
    } while (0)

#define FRAG_MFMA(T) do { \
        const char* ab_ = (const char*)&Abuf[(T) % 3][0]; \
        const char* bb_ = (const char*)&Bbuf[(T) % 3][0]; \
        bf16x8_t af_[4], bf_[2]; \
        _Pragma("unroll") \
        for (int mi = 0; mi < 4; ++mi) af_[mi] = *(const bf16x8_t*)(ab_ + offA[mi]); \
        _Pragma("unroll") \
        for (int nj = 0; nj < 2; ++nj) bf_[nj] = *(const bf16x8_t*)(bb_ + offB[nj]); \
        _Pragma("unroll") \
        for (int mi = 0; mi < 4; ++mi) \
            _Pragma("unroll") \
            for (int nj = 0; nj < 2; ++nj) \
                acc[mi][nj] = __builtin_amdgcn_mfma_f32_16x16x32_bf16( \
                    af_[mi], bf_[nj], acc[mi][nj], 0, 0, 0); \
    } while (0)

    // body for step T: issue loads for T+2 into (I0,I1); compute T; write A(T+1) from (W0,W1)
#define GEMM_STEP(T, I0, I1, W0, W1) do { \
        int k2_ = ((T) + 2) * BK; \
        I0 = *(const float4*)(srcA + k2_); \
        I1 = *(const float4*)(srcA + k2_ + 4); \
        gload_lds16(srcB + k2_, (char*)&Bbuf[((T) + 2) % 3][0] + ldsOffB); \
        FRAG_MFMA(T); \
        WRITE_A(((T) + 1) % 3, W0, W1); \
        asm volatile("s_waitcnt vmcnt(3) lgkmcnt(0)" ::: "memory"); \
        __builtin_amdgcn_sched_barrier(0); \
        __builtin_amdgcn_s_barrier(); \
        __builtin_amdgcn_sched_barrier(0); \
    } while (0)

    // prologue: issue steps 0 and 1
    pA0 = *(const float4*)(srcA);
    pA1 = *(const float4*)(srcA + 4);
    gload_lds16(srcB, (char*)&Bbuf[0][0] + ldsOffB);
    qA0 = *(const float4*)(srcA + BK);
    qA1 = *(const float4*)(srcA + BK + 4);
    gload_lds16(srcB + BK, (char*)&Bbuf[1][0] + ldsOffB);
    asm volatile("s_waitcnt vmcnt(3)" ::: "memory");   // step-0 loads done
    WRITE_A(0, pA0, pA1);
    asm volatile("s_waitcnt lgkmcnt(0)" ::: "memory");
    __builtin_amdgcn_sched_barrier(0);
    __builtin_amdgcn_s_barrier();
    __builtin_amdgcn_sched_barrier(0);

    // main pipelined loop: steps 0..nk-3 (nk=16 -> t=0..13, 7 pairs)
    for (int tt = 0; tt + 3 < nk; tt += 2) {
        GEMM_STEP(tt,     pA0, pA1, qA0, qA1);   // even: issue->p, write q=A(t+1)
        GEMM_STEP(tt + 1, qA0, qA1, pA0, pA1);   // odd:  issue->q, write p=A(t+2)
    }
    // peeled step nk-2: no new issues; write A(nk-1) from q-set
    FRAG_MFMA(nk - 2);
    WRITE_A((nk - 1) % 3, qA0, qA1);
    __syncthreads();
    // peeled step nk-1
    FRAG_MFMA(nk - 1);

#undef GEMM_STEP
#undef FRAG_MFMA
#undef WRITE_A

    const int n1 = N - n0;
    #pragma unroll
    for (int mi = 0; mi < 4; ++mi) {
        #pragma unroll
        for (int nj = 0; nj < 2; ++nj) {
            int col = bn + wc * 32 + nj * 16 + l15;
            int r0 = bm + wr * 64 + mi * 16 + hgr * 4;
            float bv = bias[col];
            #pragma unroll
            for (int e = 0; e < 4; ++e) {
                int row = r0 + e;
                float val = acc[mi][nj][e] + bv;
                if (col < n0) {
                    if (col < sigCols) val = 1.f / (1.f + expf(-val));
                    out0[(size_t)row * n0 + col] = __float2half(val);
                } else {
                    out1[(size_t)row * n1 + (col - n0)] = __float2half(val);
                }
            }
        }
    }
}

// ---------------------------------------------------------------------------
// Scan / bind device bodies. gi: [M][512] fp16 (g | in). vkq: [M][256] fp16.
// ---------------------------------------------------------------------------
__device__ void scan_pass1_body(int blk,
    const __half* __restrict__ gi,
    float* __restrict__ ca_last, float* __restrict__ wb_last)
{
    int idx = blk * 256 + threadIdx.x;        // 131072
    int sd = idx & 255;
    int c  = (idx >> 8) & 63;
    int b  = idx >> 14;
    size_t base = ((size_t)(b * TT + c * CHUNK)) * 512;
    float prod = 1.f, wb = 0.f;
    for (int i = 0; i < CHUNK; ++i) {
        size_t off = base + (size_t)i * 512;
        float g  = __half2float(gi[off + sd]);
        float il = __half2float(gi[off + 256 + sd]);
        float a = fmaxf(g, 1e-6f);
        prod *= a;
        wb += (1.f - g) * il / fmaxf(prod, 1e-8f);
    }
    int cidx = (b * NC + c) * SD + sd;
    ca_last[cidx] = prod;
    wb_last[cidx] = wb;
}

// writes states bf16 into cat[row][0..255], stride KCAT
__device__ void scan_pass3_body(int blk,
    const __half* __restrict__ gi, const float* __restrict__ h_prev,
    __hip_bfloat16* __restrict__ cat)
{
    int idx = blk * 256 + threadIdx.x;        // 131072
    int sd = idx & 255;
    int c  = (idx >> 8) & 63;
    int b  = idx >> 14;
    size_t base = ((size_t)(b * TT + c * CHUNK)) * 512;
    size_t obase = ((size_t)(b * TT + c * CHUNK)) * KCAT + sd;
    float h = h_prev[(b * NC + c) * SD + sd];
    float prod = 1.f, wb = 0.f;
    for (int i = 0; i < CHUNK; ++i) {
        size_t off = base + (size_t)i * 512;
        float g  = __half2float(gi[off + sd]);
        float il = __half2float(gi[off + 256 + sd]);
        float a = fmaxf(g, 1e-6f);
        prod *= a;
        wb += (1.f - g) * il / fmaxf(prod, 1e-8f);
        cat[obase + (size_t)i * KCAT] = __float2bfloat16(prod * (h + wb));
    }
}

#define LST 68
__device__ void bind_p1_body(int bc,
    const __half* __restrict__ vkq, const float* __restrict__ op_decay,
    float* __restrict__ o, float* __restrict__ dS,
    float* B1, float* B2, float* B3, float* l2d)
{
    const int b = bc >> 5, c = bc & 31;
    const size_t base = ((size_t)b * TT + (size_t)c * CB) * 256;
    const size_t obase = ((size_t)b * TT + (size_t)c * CB) * OD;
    const int tid = threadIdx.x;
    if (tid < 64) l2d[tid] = log2f(1.f / (1.f + expf(-op_decay[tid])));
    const int lr = tid >> 4, lc = (tid & 15) << 2;
    #pragma unroll
    for (int rr = 0; rr < 4; ++rr) {
        int t = lr + rr * 16;
        float4 qv = ldh4(&vkq[base + t * 256 + 128 + lc]);
        float4 kv = ldh4(&vkq[base + t * 256 + 64 + lc]);
        float q4[4] = {qv.x, qv.y, qv.z, qv.w};
        float k4[4] = {kv.x, kv.y, kv.z, kv.w};
        #pragma unroll
        for (int j = 0; j < 4; ++j) {
            B1[(lc + j) * LST + t] = q4[j];
            B2[(lc + j) * LST + t] = k4[j];
        }
    }
    __syncthreads();
    const int tx = tid & 15, ty = tid >> 4;
    {
        float a_acc[4][4] = {};
        for (int d = 0; d < 64; ++d) {
            float4 q4 = *(const float4*)&B1[d * LST + 4 * ty];
            float4 k4 = *(const float4*)&B2[d * LST + 4 * tx];
            float qr[4] = {q4.x, q4.y, q4.z, q4.w};
            float kr[4] = {k4.x, k4.y, k4.z, k4.w};
            #pragma unroll
            for (int r = 0; r < 4; ++r)
                #pragma unroll
                for (int s = 0; s < 4; ++s)
                    a_acc[r][s] = fmaf(qr[r], kr[s], a_acc[r][s]);
        }
        __syncthreads();
        #pragma unroll
        for (int s = 0; s < 4; ++s) {
            int ss = 4 * tx + s;
            float w[4];
            #pragma unroll
            for (int r = 0; r < 4; ++r)
                w[r] = (ss <= 4 * ty + r) ? a_acc[r][s] : 0.f;
            *(float4*)&B3[ss * LST + 4 * ty] = *(float4*)w;
        }
    }
    #pragma unroll
    for (int rr = 0; rr < 4; ++rr) {
        int m = lr + rr * 16;
        float4 vv = ldh4(&vkq[base + m * 256 + 0 + lc]);
        float4 kv = ldh4(&vkq[base + m * 256 + 64 + lc]);
        float v4[4] = {vv.x, vv.y, vv.z, vv.w};
        #pragma unroll
        for (int j = 0; j < 4; ++j)
            v4[j] *= exp2f(-(float)m * l2d[lc + j]);
        *(float4*)&B1[m * LST + lc] = *(float4*)v4;
        float k4[4] = {kv.x, kv.y, kv.z, kv.w};
        *(float4*)&B2[m * LST + lc] = *(float4*)k4;
    }
    __syncthreads();
    {
        float p[4][4] = {};
        for (int s = 0; s < 64; ++s) {
            float4 a4 = *(const float4*)&B3[s * LST + 4 * ty];
            float4 v4 = *(const float4*)&B1[s * LST + 4 * tx];
            float ar[4] = {a4.x, a4.y, a4.z, a4.w};
            float vr[4] = {v4.x, v4.y, v4.z, v4.w};
            #pragma unroll
            for (int r = 0; r < 4; ++r)
                #pragma unroll
                for (int i2 = 0; i2 < 4; ++i2)
                    p[r][i2] = fmaf(ar[r], vr[i2], p[r][i2]);
        }
        #pragma unroll
        for (int r = 0; r < 4; ++r) {
            int t = 4 * ty + r;
            float w[4];
            #pragma unroll
            for (int i2 = 0; i2 < 4; ++i2)
                w[i2] = exp2f((float)t * l2d[4 * tx + i2]) * p[r][i2];
            *(float4*)&o[obase + t * OD + 4 * tx] = *(float4*)w;
        }
    }
    {
        float sacc[4][4] = {};
        for (int m = 0; m < 64; ++m) {
            float4 v4 = *(const float4*)&B1[m * LST + 4 * ty];
            float4 k4 = *(const float4*)&B2[m * LST + 4 * tx];
            float vr[4] = {v4.x, v4.y, v4.z, v4.w};
            float kr[4] = {k4.x, k4.y, k4.z, k4.w};
            #pragma unroll
            for (int r = 0; r < 4; ++r)
                #pragma unroll
                for (int j = 0; j < 4; ++j)
                    sacc[r][j] = fmaf(vr[r], kr[j], sacc[r][j]);
        }
        float* dSb = dS + (size_t)bc * 4096;
        #pragma unroll
        for (int r = 0; r < 4; ++r) {
            int i = 4 * ty + r;
            float scale = exp2f(63.f * l2d[i]);
            float w[4];
            #pragma unroll
            for (int j2 = 0; j2 < 4; ++j2)
                w[j2] = scale * sacc[r][j2];
            *(float4*)&dSb[i * 64 + 4 * tx] = *(float4*)w;
        }
    }
}

// o_final(bf16 into cat[row][256+i]) = o_intra + dec^(l+1) * (Q @ Sstart^T)
__device__ void bind_p3_body(int bc,
    const __half* __restrict__ vkq, const float* __restrict__ Sstart,
    const float* __restrict__ op_decay, const float* __restrict__ o,
    __hip_bfloat16* __restrict__ cat,
    float* B1, float* B2, float* l2d)
{
    const int b = bc >> 5, c = bc & 31;
    const size_t base = ((size_t)b * TT + (size_t)c * CB) * 256;
    const size_t obase = ((size_t)b * TT + (size_t)c * CB) * OD;
    const size_t cbase = ((size_t)b * TT + (size_t)c * CB) * KCAT + 256;
    const int tid = threadIdx.x;
    if (tid < 64) l2d[tid] = log2f(1.f / (1.f + expf(-op_decay[tid])));
    const int lr = tid >> 4, lc = (tid & 15) << 2;
    const float* Sb = Sstart + (size_t)bc * 4096;
    #pragma unroll
    for (int rr = 0; rr < 4; ++rr) {
        int t = lr + rr * 16;
        float4 qv = ldh4(&vkq[base + t * 256 + 128 + lc]);
        float4 sv = *(const float4*)&Sb[t * 64 + lc];
        float q4[4] = {qv.x, qv.y, qv.z, qv.w};
        float s4[4] = {sv.x, sv.y, sv.z, sv.w};
        #pragma unroll
        for (int j = 0; j < 4; ++j) {
            B1[(lc + j) * LST + t] = q4[j];
            B2[(lc + j) * LST + t] = s4[j];
        }
    }
    __syncthreads();
    const int tx = tid & 15, ty = tid >> 4;
    float acc[4][4] = {};
    for (int j = 0; j < 64; ++j) {
        float4 q4 = *(const float4*)&B1[j * LST + 4 * ty];
        float4 s4 = *(const float4*)&B2[j * LST + 4 * tx];
        float qr[4] = {q4.x, q4.y, q4.z, q4.w};
        float sr[4] = {s4.x, s4.y, s4.z, s4.w};
        #pragma unroll
        for (int r = 0; r < 4; ++r)
            #pragma unroll
            for (int i2 = 0; i2 < 4; ++i2)
                acc[r][i2] = fmaf(qr[r], sr[i2], acc[r][i2]);
    }
    #pragma unroll
    for (int r = 0; r < 4; ++r) {
        int l = 4 * ty + r;
        alignas(8) __hip_bfloat16 w[4];
        #pragma unroll
        for (int i2 = 0; i2 < 4; ++i2) {
            int i = 4 * tx + i2;
            float val = o[obase + l * OD + i] + exp2f((float)(l + 1) * l2d[i]) * acc[r][i2];
            w[i2] = __float2bfloat16(val);
        }
        *(float2*)&cat[cbase + l * KCAT + 4 * tx] = *(float2*)w;
    }
}

// fused1: blocks 0-255 -> bind_p1, blocks 256-767 -> scan_pass1
__global__ __launch_bounds__(256) void fused1(
    const __half* __restrict__ gi, const __half* __restrict__ vkq,
    const float* __restrict__ op_decay,
    float* __restrict__ ca_last, float* __restrict__ wb_last,
    float* __restrict__ o_intra, float* __restrict__ dS)
{
    __shared__ float B1[64 * LST];
    __shared__ float B2[64 * LST];
    __shared__ float B3[64 * LST];
    __shared__ float l2d[64];
    const int bid = blockIdx.x;
    if (bid < 256) bind_p1_body(bid, vkq, op_decay, o_intra, dS, B1, B2, B3, l2d);
    else           scan_pass1_body(bid - 256, gi, ca_last, wb_last);
}

// fused2: blocks 0-127 -> bind_p2 carry; 128-135 -> scan_pass2;
//         blocks 136+  -> Wcomb/bias_comb prep (idle capacity)
__global__ __launch_bounds__(256) void fused2(
    const float* __restrict__ dS, const float* __restrict__ op_decay,
    float* __restrict__ Sstart,
    const float* __restrict__ ca_last, const float* __restrict__ wb_last,
    float* __restrict__ h_prev,
    const float* __restrict__ out_W, const float* __restrict__ out_b,
    const float* __restrict__ opout_W, const float* __restrict__ opout_b,
    __hip_bfloat16* __restrict__ Wcomb, float* __restrict__ bias_comb)
{
    const int bid = blockIdx.x;
    if (bid < 128) {
        int idx = bid * 256 + threadIdx.x;   // 32768
        int j = idx & 63, i = (idx >> 6) & 63, b = idx >> 12;
        float dec = 1.f / (1.f + expf(-op_decay[i]));
        float d64 = exp2f(64.f * log2f(dec));
        float S = 0.f;
        for (int c = 0; c < NCB; ++c) {
            size_t o = (((size_t)b * NCB + c) * 4096) + i * 64 + j;
            Sstart[o] = S;
            S = d64 * S + dS[o];
        }
    } else if (bid < 136) {
        int idx = (bid - 128) * 256 + threadIdx.x;   // 2048
        int sd = idx & 255;
        int b  = idx >> 8;
        float h = 0.f;
        for (int c = 0; c < NC; ++c) {
            int o = (b * NC + c) * SD + sd;
            h_prev[o] = h;
            h = ca_last[o] * (h + wb_last[o]);
        }
    } else {
        int idx = (bid - 136) * 256 + threadIdx.x;
        if (idx < 163840) {                       // Wcomb [512][320]
            int n = idx / KCAT, k = idx % KCAT;
            float v = (k < 256) ? out_W[k * 512 + n] : opout_W[(k - 256) * 512 + n];
            Wcomb[idx] = __float2bfloat16(v);
            return;
        }
        idx -= 163840;
        if (idx < 512) bias_comb[idx] = out_b[idx] + opout_b[idx];
    }
}

// fused3: blocks 0-255 -> bind_p3 (cat cols 256-319), 256-767 -> scan_pass3 (cols 0-255)
__global__ __launch_bounds__(256) void fused3(
    const __half* __restrict__ gi, const float* __restrict__ h_prev,
    const __half* __restrict__ vkq, const float* __restrict__ Sstart,
    const float* __restrict__ op_decay, const float* __restrict__ o_intra,
    __hip_bfloat16* __restrict__ cat)
{
    __shared__ float B1[64 * LST];
    __shared__ float B2[64 * LST];
    __shared__ float l2d[64];
    const int bid = blockIdx.x;
    if (bid < 256) bind_p3_body(bid, vkq, Sstart, op_decay, o_intra, cat, B1, B2, l2d);
    else           scan_pass3_body(bid - 256, gi, h_prev, cat);
}

// ---------------------------------------------------------------------------
// Fused output GEMM + residual + LayerNorm.
// y = LN(x + cat @ Wcomb^T + bias_comb) * ln_g + ln_b
// BM=32, BN=512 (full rows per block), BK=32, 512 threads (8 waves, 1x8),
// wave tile 32x64, double-buffered global_load_lds with granule swizzle.
// ---------------------------------------------------------------------------
__global__ __launch_bounds__(512) void outgemm_ln(
    const __hip_bfloat16* __restrict__ cat,    // [M][320]
    const __hip_bfloat16* __restrict__ Wcomb,  // [512][320]
    const float* __restrict__ bias_comb,
    const float* __restrict__ x,               // [M][512]
    const float* __restrict__ lng, const float* __restrict__ lnb,
    float* __restrict__ y)
{
    constexpr int BM = 32, BK = 32, NN = 512;
    __shared__ alignas(16) __hip_bfloat16 As[2][BM * BK];     // 2x2KB
    __shared__ alignas(16) __hip_bfloat16 Bs[2][NN * BK];     // 2x32KB
    __shared__ float psum[8][BM], psum2[8][BM], mvmu[BM], mvrs[BM];
    const int tid = threadIdx.x;
    const int lane = tid & 63, wid = tid >> 6;
    const int l15 = lane & 15, hgr = lane >> 4;
    const int bm = blockIdx.x * BM;

    // A staging (waves 0-1 only)
    const __hip_bfloat16* srcA = cat;
    int ldsOffA = 0;
    {
        int gg = (wid & 1) * 64 + lane;
        int row = gg >> 2, sl = (gg & 3) ^ ((row >> 1) & 3);
        srcA = cat + (size_t)(bm + row) * KCAT + sl * 8;
        ldsOffA = (wid & 1) * 1024;
    }
    // B staging: 4 calls per wave
    const __hip_bfloat16* srcB[4];
    int ldsOffB[4];
    #pragma unroll
    for (int c = 0; c < 4; ++c) {
        int gg = (wid * 4 + c) * 64 + lane;
        int row = gg >> 2, sl = (gg & 3) ^ ((row >> 1) & 3);
        srcB[c] = Wcomb + (size_t)row * KCAT + sl * 8;
        ldsOffB[c] = (wid * 4 + c) * 1024;
    }
    int offA[2], offB[4];
    #pragma unroll
    for (int mi = 0; mi < 2; ++mi) {
        int r = mi * 16 + l15;
        offA[mi] = r * 64 + (hgr ^ ((r >> 1) & 3)) * 16;
    }
    #pragma unroll
    for (int nj = 0; nj < 4; ++nj) {
        int n = wid * 64 + nj * 16 + l15;
        offB[nj] = n * 64 + (hgr ^ ((n >> 1) & 3)) * 16;
    }

    f32x4 acc[2][4] = {};
    constexpr int nk = KCAT / BK;   // 10

    if (wid < 2) gload_lds16(srcA, (char*)&As[0][0] + ldsOffA);
    #pragma unroll
    for (int c = 0; c < 4; ++c) gload_lds16(srcB[c], (char*)&Bs[0][0] + ldsOffB[c]);
    __syncthreads();

    int cur = 0;
    for (int t = 0; t < nk; ++t) {
        if (t + 1 < nk) {
            int k0 = (t + 1) * BK;
            if (wid < 2) gload_lds16(srcA + k0, (char*)&As[cur ^ 1][0] + ldsOffA);
            #pragma unroll
            for (int c = 0; c < 4; ++c)
                gload_lds16(srcB[c] + k0, (char*)&Bs[cur ^ 1][0] + ldsOffB[c]);
        }
        bf16x8_t af[2], bfr[4];
        #pragma unroll
        for (int mi = 0; mi < 2; ++mi)
            af[mi] = *(const bf16x8_t*)((const char*)&As[cur][0] + offA[mi]);
        #pragma unroll
        for (int nj = 0; nj < 4; ++nj)
            bfr[nj] = *(const bf16x8_t*)((const char*)&Bs[cur][0] + offB[nj]);
        #pragma unroll
        for (int mi = 0; mi < 2; ++mi)
            #pragma unroll
            for (int nj = 0; nj < 4; ++nj)
                acc[mi][nj] = __builtin_amdgcn_mfma_f32_16x16x32_bf16(
                    af[mi], bfr[nj], acc[mi][nj], 0, 0, 0);
        __syncthreads();
        cur ^= 1;
    }

    // epilogue: + bias + x residual
    #pragma unroll
    for (int nj = 0; nj < 4; ++nj) {
        int col = wid * 64 + nj * 16 + l15;
        float bc_ = bias_comb[col];
        #pragma unroll
        for (int mi = 0; mi < 2; ++mi) {
            int r0 = bm + mi * 16 + hgr * 4;
            #pragma unroll
            for (int e = 0; e < 4; ++e)
                acc[mi][nj][e] += bc_ + x[(size_t)(r0 + e) * DD + col];
        }
    }
    // per-row sums over this wave's 64 cols
    float s[8], s2[8];
    #pragma unroll
    for (int mi = 0; mi < 2; ++mi)
        #pragma unroll
        for (int e = 0; e < 4; ++e) {
            float a = 0.f, b2 = 0.f;
            #pragma unroll
            for (int nj = 0; nj < 4; ++nj) {
                float v = acc[mi][nj][e];
                a += v; b2 += v * v;
            }
            s[mi * 4 + e] = a; s2[mi * 4 + e] = b2;
        }
    #pragma unroll
    for (int off = 1; off <= 8; off <<= 1)
        #pragma unroll
        for (int i = 0; i < 8; ++i) {
            s[i]  += __shfl_xor(s[i], off);
            s2[i] += __shfl_xor(s2[i], off);
        }
    if (l15 == 0) {
        #pragma unroll
        for (int mi = 0; mi < 2; ++mi)
            #pragma unroll
            for (int e = 0; e < 4; ++e) {
                int lr = mi * 16 + hgr * 4 + e;
                psum[wid][lr]  = s[mi * 4 + e];
                psum2[wid][lr] = s2[mi * 4 + e];
            }
    }
    __syncthreads();
    if (tid < BM) {
        float tot = 0.f, tot2 = 0.f;
        #pragma unroll
        for (int w2 = 0; w2 < 8; ++w2) { tot += psum[w2][tid]; tot2 += psum2[w2][tid]; }
        float mu = tot * (1.f / 512.f);
        float var = tot2 * (1.f / 512.f) - mu * mu;
        mvmu[tid] = mu;
        mvrs[tid] = rsqrtf(var + 1e-5f);
    }
    __syncthreads();
    #pragma unroll
    for (int nj = 0; nj < 4; ++nj) {
        int col = wid * 64 + nj * 16 + l15;
        float g = lng[col], bb = lnb[col];
        #pragma unroll
        for (int mi = 0; mi < 2; ++mi) {
            #pragma unroll
            for (int e = 0; e < 4; ++e) {
                int lr = mi * 16 + hgr * 4 + e;
                y[(size_t)(bm + lr) * DD + col] =
                    (acc[mi][nj][e] - mvmu[lr]) * mvrs[lr] * g + bb;
            }
        }
    }
}

// ---------------------------------------------------------------------------
extern "C" void kernel_launch(void* const* d_in, const int* in_sizes, int n_in,
                              void* d_out, int out_size, void* d_ws, size_t ws_size,
                              hipStream_t stream)
{
    const float* x       = (const float*)d_in[0];
    const float* gate_W  = (const float*)d_in[1];
    const float* gate_b  = (const float*)d_in[2];
    const float* in_W    = (const float*)d_in[3];
    const float* in_b    = (const float*)d_in[4];
    const float* out_W   = (const float*)d_in[5];
    const float* out_b   = (const float*)d_in[6];
    const float* opv_W   = (const float*)d_in[7];
    const float* opv_b   = (const float*)d_in[8];
    const float* opk_W   = (const float*)d_in[9];
    const float* opk_b   = (const float*)d_in[10];
    const float* opq_W   = (const float*)d_in[11];
    const float* opq_b   = (const float*)d_in[12];
    const float* op_dec  = (const float*)d_in[13];
    const float* opout_W = (const float*)d_in[14];
    const float* opout_b = (const float*)d_in[15];
    const float* ln_g    = (const float*)d_in[16];
    const float* ln_b    = (const float*)d_in[17];
    float* y = (float*)d_out;

    char* w = (char*)d_ws;
    auto alloc = [&](size_t bytes) { char* p = w; w += (bytes + 255) & ~(size_t)255; return p; };
    __half* gi       = (__half*)alloc((size_t)MM * 512 * 2);
    __half* vkq      = (__half*)alloc((size_t)MM * 256 * 2);
    float* o_intra   = (float*)alloc((size_t)MM * 64 * 4);
    float* ca_last   = (float*)alloc((size_t)BB * NC * SD * 4);
    float* wb_last   = (float*)alloc((size_t)BB * NC * SD * 4);
    float* h_prev    = (float*)alloc((size_t)BB * NC * SD * 4);
    float* dS        = (float*)alloc((size_t)BB * NCB * 4096 * 4);
    float* Sstart    = (float*)alloc((size_t)BB * NCB * 4096 * 4);
    float* bias_cat  = (float*)alloc(768 * 4);
    float* bias_comb = (float*)alloc(512 * 4);
    __hip_bfloat16* cat   = (__hip_bfloat16*)alloc((size_t)MM * KCAT * 2);
    __hip_bfloat16* Wcat  = (__hip_bfloat16*)alloc((size_t)768 * 512 * 2);
    __hip_bfloat16* Wcomb = (__hip_bfloat16*)alloc((size_t)512 * KCAT * 2);

    // 1: weight prep (Wcat + bias_cat only)
    hipLaunchKernelGGL(conv_w, dim3((393216 + 768 + 255) / 256), dim3(256), 0, stream,
                       gate_W, gate_b, in_W, in_b, opv_W, opk_W, opq_W,
                       opv_b, opk_b, opq_b, Wcat, bias_cat);
    // 2: fused projection from fp32 x (fp16 outputs, XCD-swizzled grid 768 = 8*96)
    hipLaunchKernelGGL(gemm_proj, dim3(6 * (MM / 128)), dim3(512), 0, stream,
                       x, Wcat, bias_cat, gi, vkq,
                       MM, 768, 512, 512, 256);
    // 3: bind_p1 || scan_pass1
    hipLaunchKernelGGL(fused1, dim3(768), dim3(256), 0, stream,
                       gi, vkq, op_dec, ca_last, wb_last, o_intra, dS);
    // 4: carry scans + Wcomb prep in idle blocks
    hipLaunchKernelGGL(fused2, dim3(136 + (163840 + 512 + 255) / 256), dim3(256), 0, stream,
                       dS, op_dec, Sstart, ca_last, wb_last, h_prev,
                       out_W, out_b, opout_W, opout_b, Wcomb, bias_comb);
    // 5: bind_p3 || scan_pass3 -> cat[M][320] bf16
    hipLaunchKernelGGL(fused3, dim3(768), dim3(256), 0, stream,
                       gi, h_prev, vkq, Sstart, op_dec, o_intra, cat);
    // 6: y = LN(x + cat @ Wcomb^T + bias_comb)
    hipLaunchKernelGGL(outgemm_ln, dim3(MM / 32), dim3(512), 0, stream,
                       cat, Wcomb, bias_comb, x, ln_g, ln_b, y);
}